// Round 10
// baseline (113.566 us; speedup 1.0000x reference)
//
#include <hip/hip_runtime.h>
#include <hip/hip_bf16.h>
#include <stdint.h>

#define NN 2048
#define LOG2NN 11
#define GK 2048
#define GNC 2048

typedef __bf16 bf16x8 __attribute__((ext_vector_type(8)));
typedef float f32x4 __attribute__((ext_vector_type(4)));

// round-to-nearest-even f32 -> bf16 bits
__device__ __forceinline__ ushort f2bf(float f) {
  uint32_t x = __float_as_uint(f);
  uint32_t r = (x + 0x7fffu + ((x >> 16) & 1u)) >> 16;
  return (ushort)r;
}

__device__ __forceinline__ int lower_bound32(const int* __restrict__ a, int n, int v) {
  int lo = 0, hi = n;
  while (lo < hi) {
    int mid = (lo + hi) >> 1;
    if (a[mid] < v) lo = mid + 1; else hi = mid;
  }
  return lo;
}

// ---------------------------------------------------------------- prep (fused)
// blocks [0,2048): transpose W1/W2 f32 -> bf16^T (64x64 tiles)
// blocks [2048,2560): per-row softmax + column histogram.
// hist/uW/ecnt zeroed by hipMemsetAsync BEFORE this launch (round-8 lesson).
__global__ __launch_bounds__(256) void prep_kernel(
    const float* __restrict__ W1, const float* __restrict__ W2,
    ushort* __restrict__ WT, ushort* __restrict__ W2T,
    int* __restrict__ hist, int* __restrict__ ecnt,
    const int* __restrict__ idx, const float* __restrict__ e, int nnz,
    float* __restrict__ vals, float* __restrict__ diag, int* __restrict__ empty) {
  __shared__ float tile[64][65];
  const int bid = blockIdx.x;
  const int t = threadIdx.x;
  if (bid < 2048) {  // transpose: out[c][r] = (bf16) in[r][c]
    const int m = bid >> 10;            // 0 = W1, 1 = W2
    const int rem = bid & 1023;
    const int r0 = (rem >> 5) * 64, c0 = (rem & 31) * 64;
    const float* in = m ? W2 : W1;
    ushort* out = m ? W2T : WT;
    const int tx = t & 15, ty = t >> 4;
#pragma unroll
    for (int i = 0; i < 4; ++i) {
      int r = i * 16 + ty;
      float4 v = *reinterpret_cast<const float4*>(&in[(size_t)(r0 + r) * NN + c0 + tx * 4]);
      tile[r][tx * 4 + 0] = v.x;
      tile[r][tx * 4 + 1] = v.y;
      tile[r][tx * 4 + 2] = v.z;
      tile[r][tx * 4 + 3] = v.w;
    }
    __syncthreads();
#pragma unroll
    for (int i = 0; i < 4; ++i) {
      int oc = i * 16 + ty;  // output row = original col
      ushort4 o;
      o.x = f2bf(tile[tx * 4 + 0][oc]);
      o.y = f2bf(tile[tx * 4 + 1][oc]);
      o.z = f2bf(tile[tx * 4 + 2][oc]);
      o.w = f2bf(tile[tx * 4 + 3][oc]);
      *reinterpret_cast<ushort4*>(&out[(size_t)(c0 + oc) * NN + r0 + tx * 4]) = o;
    }
  } else {  // softmax + hist: wave w handles row r
    const int w = t >> 6, lane = t & 63;
    const int r = (bid - 2048) * 4 + w;
    int lo = lower_bound32(idx, nnz, r << LOG2NN);
    int hi = lower_bound32(idx, nnz, (r + 1) << LOG2NN);
    if (hi <= lo) {  // empty row: softmax of all-equal NEG -> uniform 1/NN
      if (lane == 0) { diag[r] = 1.0f / NN; empty[r] = 1; atomicAdd(ecnt, 1); }
      return;
    }
    float m = -3.0e38f;
    for (int j = lo + lane; j < hi; j += 64) m = fmaxf(m, e[j]);
#pragma unroll
    for (int s = 32; s >= 1; s >>= 1) m = fmaxf(m, __shfl_xor(m, s));
    float sum = 0.f;
    for (int j = lo + lane; j < hi; j += 64) sum += expf(e[j] - m);
#pragma unroll
    for (int s = 32; s >= 1; s >>= 1) sum += __shfl_xor(sum, s);
    float inv = 1.0f / sum;
    float dv = 0.f;
    for (int j = lo + lane; j < hi; j += 64) {
      float v = expf(e[j] - m) * inv;
      vals[j] = v;
      int c = idx[j] & (NN - 1);
      if (c == r) dv = v;
      else atomicAdd(&hist[c], 1);
    }
#pragma unroll
    for (int s = 32; s >= 1; s >>= 1) dv += __shfl_xor(dv, s);
    if (lane == 0) { diag[r] = dv; empty[r] = 0; }
  }
}

// ---------------------------------------------------------------- scan + uw (fused)
__global__ __launch_bounds__(256) void scan_uw_kernel(
    const int* __restrict__ hist, int* __restrict__ base, int* __restrict__ cursor,
    const float* __restrict__ W2, const int* __restrict__ empty,
    const int* __restrict__ ecnt, float* __restrict__ uW) {
  if (blockIdx.x == 0) {
    const int l = threadIdx.x;
    if (l >= 64) return;
    int vals[32], pre[32];
    int run = 0;
#pragma unroll
    for (int j = 0; j < 32; ++j) {
      vals[j] = hist[l * 32 + j];
      pre[j] = run;
      run += vals[j];
    }
    int tot = run, inc = run;
#pragma unroll
    for (int s = 1; s < 64; s <<= 1) {
      int o = __shfl_up(inc, s);
      if (l >= s) inc += o;
    }
    int excl = inc - tot;
#pragma unroll
    for (int j = 0; j < 32; ++j) {
      int b = excl + pre[j];
      base[l * 32 + j] = b;
      cursor[l * 32 + j] = b;
    }
  } else {
    if (*ecnt == 0) return;
    int p = (blockIdx.x - 1) * 256 + threadIdx.x;
    float s = 0.f;
    for (int k = 0; k < NN; ++k)
      if (empty[k]) s += W2[(size_t)p * NN + k];
    uW[p] = s * (1.0f / NN);
  }
}

// ---------------------------------------------------------------- scatter by column
__global__ void scatter_kernel(const int* __restrict__ idx, const float* __restrict__ vals,
                               int nnz, int* __restrict__ cursor,
                               int* __restrict__ ek, float* __restrict__ ev) {
  int j = blockIdx.x * blockDim.x + threadIdx.x;
  if (j >= nnz) return;
  int f = idx[j];
  int c = f & (NN - 1), r = f >> LOG2NN;
  if (c != r) {
    int p = atomicAdd(&cursor[c], 1);
    ek[p] = r;
    ev[p] = vals[j];
  }
}

// ---------------------------------------------------------------- SpMM + x-convert
__global__ __launch_bounds__(256) void spmm_kernel(
    const int* __restrict__ ek, const float* __restrict__ ev,
    const int* __restrict__ base, const int* __restrict__ hist,
    const ushort* __restrict__ W2T,
    const float* __restrict__ diag, const int* __restrict__ empty,
    const float* __restrict__ uW, ushort* WT,
    const float* __restrict__ x, ushort* __restrict__ xb) {
  if (blockIdx.x >= 1024) {  // x convert: 4096 blocks x 256 thr x 8 floats
    int i = ((int)blockIdx.x - 1024) * 256 + threadIdx.x;
    const float4* in4 = reinterpret_cast<const float4*>(x);
    float4 a = in4[2 * i];
    float4 b = in4[2 * i + 1];
    uint4 o;
    o.x = (uint32_t)f2bf(a.x) | ((uint32_t)f2bf(a.y) << 16);
    o.y = (uint32_t)f2bf(a.z) | ((uint32_t)f2bf(a.w) << 16);
    o.z = (uint32_t)f2bf(b.x) | ((uint32_t)f2bf(b.y) << 16);
    o.w = (uint32_t)f2bf(b.z) | ((uint32_t)f2bf(b.w) << 16);
    reinterpret_cast<uint4*>(xb)[i] = o;
    return;
  }
  const int w = threadIdx.x >> 6, lane = threadIdx.x & 63;
  const int n = blockIdx.x * 2 + (w >> 1);
  const int c0 = (w & 1) * 1024 + lane * 16;  // groups at c0, c0+8
  const int start = base[n], cnt = hist[n];
  float acc[2][8];
#pragma unroll
  for (int g = 0; g < 2; ++g) {
    float4 u0 = *reinterpret_cast<const float4*>(&uW[c0 + g * 8]);
    float4 u1 = *reinterpret_cast<const float4*>(&uW[c0 + g * 8 + 4]);
    acc[g][0] = u0.x; acc[g][1] = u0.y; acc[g][2] = u0.z; acc[g][3] = u0.w;
    acc[g][4] = u1.x; acc[g][5] = u1.y; acc[g][6] = u1.z; acc[g][7] = u1.w;
  }
  float d = diag[n];  // diag term first (reads WT range before overwriting)
  if (d != 0.f) {
#pragma unroll
    for (int g = 0; g < 2; ++g) {
      bf16x8 wd = *reinterpret_cast<const bf16x8*>(&WT[(size_t)n * NN + c0 + g * 8]);
#pragma unroll
      for (int j = 0; j < 8; ++j) acc[g][j] += d * (float)wd[j];
    }
  }
  int i = 0;
  for (; i + 4 <= cnt; i += 4) {
    int k[4];
    float v[4];
    bf16x8 wv[4][2];
#pragma unroll
    for (int e2 = 0; e2 < 4; ++e2) {
      k[e2] = ek[start + i + e2];
      v[e2] = ev[start + i + e2];
    }
#pragma unroll
    for (int e2 = 0; e2 < 4; ++e2)
#pragma unroll
      for (int g = 0; g < 2; ++g)
        wv[e2][g] = *reinterpret_cast<const bf16x8*>(&W2T[(size_t)k[e2] * NN + c0 + g * 8]);
#pragma unroll
    for (int e2 = 0; e2 < 4; ++e2)
#pragma unroll
      for (int g = 0; g < 2; ++g)
#pragma unroll
        for (int j = 0; j < 8; ++j)
          acc[g][j] += v[e2] * (float)wv[e2][g][j];
  }
  for (; i < cnt; ++i) {
    int k0 = ek[start + i];
    float v0 = ev[start + i];
#pragma unroll
    for (int g = 0; g < 2; ++g) {
      bf16x8 w0 = *reinterpret_cast<const bf16x8*>(&W2T[(size_t)k0 * NN + c0 + g * 8]);
#pragma unroll
      for (int j = 0; j < 8; ++j) acc[g][j] += v0 * (float)w0[j];
    }
  }
  if (empty[n]) {
#pragma unroll
    for (int g = 0; g < 2; ++g) {
      bf16x8 we = *reinterpret_cast<const bf16x8*>(&W2T[(size_t)n * NN + c0 + g * 8]);
#pragma unroll
      for (int j = 0; j < 8; ++j) acc[g][j] -= (1.0f / NN) * (float)we[j];
    }
  }
#pragma unroll
  for (int g = 0; g < 2; ++g) {
    uint4 o;
    o.x = (uint32_t)f2bf(acc[g][0]) | ((uint32_t)f2bf(acc[g][1]) << 16);
    o.y = (uint32_t)f2bf(acc[g][2]) | ((uint32_t)f2bf(acc[g][3]) << 16);
    o.z = (uint32_t)f2bf(acc[g][4]) | ((uint32_t)f2bf(acc[g][5]) << 16);
    o.w = (uint32_t)f2bf(acc[g][6]) | ((uint32_t)f2bf(acc[g][7]) << 16);
    *reinterpret_cast<uint4*>(&WT[(size_t)n * NN + c0 + g * 8]) = o;
  }
}

// ---------------------------------------------------------------- 256x128 fine-phase GEMM
// BM=256, BN=128, BK=64, 512 thr (8 waves, 4M x 2N, 64x64/wave). LDS 96KB:
// A chunks [buf][ks][half] 8KB each (128 rows x 64B), B chunks [buf][ks] 8KB.
// 2 phases/K-tile (ks0, ks1): {8 ds_reads; 3 chunk-stages; vmcnt(6); barrier;
// lgkmcnt(0); setprio(1); 16 MFMA; setprio(0); barrier}. Contiguous 1KB
// fragment reads (conflict-free, no swizzle); stages target chunks freed one
// phase earlier; vmcnt(6) = 6 youngest chunk-stages in flight, seals every
// chunk one barrier before its readers (cross-wave safe).
__device__ __forceinline__ void gload_lds16(const ushort* g, char* l) {
  __builtin_amdgcn_global_load_lds(
      (__attribute__((address_space(1))) uint32_t*)(uintptr_t)g,
      (__attribute__((address_space(3))) uint32_t*)l, 16, 0, 0);
}

#define NT 32  // K-tiles (2048/64)

__global__ __launch_bounds__(512, 2)
void gemm8_kernel(const ushort* __restrict__ A, const ushort* __restrict__ Bt,
                  float* __restrict__ Cf) {
  __shared__ __align__(16) char smem[98304];  // A: 2buf x 2ks x 2half x 8KB | B @64KB: 2buf x 2ks x 8KB
  const int t = threadIdx.x;
  const int wid = t >> 6, lane = t & 63;
  const int wm = wid >> 1, wn = wid & 1;     // 4M x 2N wave grid
  const int fr = lane & 15, fg = lane >> 4;

  // XCD-aware swizzle (256 blocks, 256%8==0 -> bijective)
  const int swz = ((int)blockIdx.x & 7) * 32 + ((int)blockIdx.x >> 3);
  const int m0 = (swz >> 4) * 256;
  const int n0 = (swz & 15) * 128;

  // staging: chunk = 128 rows x 64B; thread covers row wid*16+(lane>>2),
  // 16B slot (lane&3). LDS dest linear (wave-uniform base + lane*16 by HW).
  const int crow = wid * 16 + (lane >> 2);
  const int ccol = (lane & 3) * 8;  // elements

#define STGA(H, KS, TAU)                                                       \
  gload_lds16(A + (size_t)(m0 + (H) * 128 + crow) * GK + (TAU) * 64 + (KS) * 32 + ccol, \
              smem + ((TAU) & 1) * 32768 + (KS) * 16384 + (H) * 8192 + wid * 1024)
#define STGB(KS, TAU)                                                          \
  gload_lds16(Bt + (size_t)(n0 + crow) * GK + (TAU) * 64 + (KS) * 32 + ccol,   \
              smem + 65536 + ((TAU) & 1) * 16384 + (KS) * 8192 + wid * 1024)

  f32x4 acc[4][4] = {};

  // prologue: tile0 all 6 chunks + tile1 ks0 (3 chunks)
  STGA(0, 0, 0); STGA(1, 0, 0); STGB(0, 0);
  STGA(0, 1, 0); STGA(1, 1, 0); STGB(1, 0);
  STGA(0, 0, 1); STGA(1, 0, 1); STGB(0, 1);
  asm volatile("s_waitcnt vmcnt(6)" ::: "memory");  // tile0-ks0 landed
  __builtin_amdgcn_s_barrier();
  asm volatile("" ::: "memory");

  for (int kt = 0; kt < NT; ++kt) {
    const int b = kt & 1;
    const int t1 = (kt + 1) & (NT - 1), t2 = (kt + 2) & (NT - 1);
    const char* Ab = smem + b * 32768;
    const char* Bb = smem + 65536 + b * 16384;
    bf16x8 aF[4], bF[4];

    // ======== phase ks0: read (b,ks0); stage tile t+1's ks1 chunks ========
#pragma unroll
    for (int mf = 0; mf < 4; ++mf) {
      const int row = wm * 64 + mf * 16 + fr;
      aF[mf] = *reinterpret_cast<const bf16x8*>(
          Ab + (row >> 7) * 8192 + (row & 127) * 64 + fg * 16);
    }
#pragma unroll
    for (int nf = 0; nf < 4; ++nf) {
      const int row = wn * 64 + nf * 16 + fr;
      bF[nf] = *reinterpret_cast<const bf16x8*>(Bb + row * 64 + fg * 16);
    }
    STGA(0, 1, t1); STGA(1, 1, t1); STGB(1, t1);
    asm volatile("s_waitcnt vmcnt(6)" ::: "memory");  // seals (b,ks1) for next phase
    __builtin_amdgcn_s_barrier();
    asm volatile("s_waitcnt lgkmcnt(0)" ::: "memory");
    __builtin_amdgcn_sched_barrier(0);
    __builtin_amdgcn_s_setprio(1);
#pragma unroll
    for (int mf = 0; mf < 4; ++mf)
#pragma unroll
      for (int nf = 0; nf < 4; ++nf)
        acc[mf][nf] = __builtin_amdgcn_mfma_f32_16x16x32_bf16(
            aF[mf], bF[nf], acc[mf][nf], 0, 0, 0);
    __builtin_amdgcn_s_setprio(0);
    __builtin_amdgcn_s_barrier();
    asm volatile("" ::: "memory");

    // ======== phase ks1: read (b,ks1); stage tile t+2's ks0 chunks ========
#pragma unroll
    for (int mf = 0; mf < 4; ++mf) {
      const int row = wm * 64 + mf * 16 + fr;
      aF[mf] = *reinterpret_cast<const bf16x8*>(
          Ab + 16384 + (row >> 7) * 8192 + (row & 127) * 64 + fg * 16);
    }
#pragma unroll
    for (int nf = 0; nf < 4; ++nf) {
      const int row = wn * 64 + nf * 16 + fr;
      bF[nf] = *reinterpret_cast<const bf16x8*>(Bb + 8192 + row * 64 + fg * 16);
    }
    STGA(0, 0, t2); STGA(1, 0, t2); STGB(0, t2);   // into (b,ks0), freed after ph-ks0
    asm volatile("s_waitcnt vmcnt(6)" ::: "memory");  // seals (b^1,ks0) for next tile
    __builtin_amdgcn_s_barrier();
    asm volatile("s_waitcnt lgkmcnt(0)" ::: "memory");
    __builtin_amdgcn_sched_barrier(0);
    __builtin_amdgcn_s_setprio(1);
#pragma unroll
    for (int mf = 0; mf < 4; ++mf)
#pragma unroll
      for (int nf = 0; nf < 4; ++nf)
        acc[mf][nf] = __builtin_amdgcn_mfma_f32_16x16x32_bf16(
            aF[mf], bF[nf], acc[mf][nf], 0, 0, 0);
    __builtin_amdgcn_s_setprio(0);
    __builtin_amdgcn_s_barrier();
    asm volatile("" ::: "memory");
  }

  asm volatile("s_waitcnt vmcnt(0)" ::: "memory");  // drain tail stages
  const int cr = lane >> 4, cc = lane & 15;
#pragma unroll
  for (int mf = 0; mf < 4; ++mf)
#pragma unroll
    for (int nf = 0; nf < 4; ++nf)
#pragma unroll
      for (int q = 0; q < 4; ++q) {
        int gm = m0 + wm * 64 + mf * 16 + cr * 4 + q;
        int gn = n0 + wn * 64 + nf * 16 + cc;
        Cf[(size_t)gm * GNC + gn] = acc[mf][nf][q];
      }
}

// ---------------------------------------------------------------- launch
extern "C" void kernel_launch(void* const* d_in, const int* in_sizes, int n_in,
                              void* d_out, int out_size, void* d_ws, size_t ws_size,
                              hipStream_t stream) {
  const float* x   = (const float*)d_in[0];  // [8,512,2048] -> [4096][2048]
  const float* W1  = (const float*)d_in[1];  // [2048][2048]
  const float* W2  = (const float*)d_in[2];  // [2048][2048]
  const float* e   = (const float*)d_in[3];  // [nnz]
  const int*   eix = (const int*)d_in[4];    // [nnz] sorted flat indices
  const int nnz = in_sizes[3];
  float* out = (float*)d_out;                // [4096][2048] fp32

  // ws layout: 34.39 MB total (proven-safe size). hist|uW|ecnt contiguous.
  char* w = (char*)d_ws;
  ushort* W2T  = (ushort*)w; w += (size_t)NN * NN * 2;    // 8.4 MB  W2^T bf16 [k][p]
  ushort* WT   = (ushort*)w; w += (size_t)NN * NN * 2;    // 8.4 MB  W1^T then Wfused^T [n][p]
  ushort* xb   = (ushort*)w; w += (size_t)4096 * NN * 2;  // 16.8 MB x bf16 [m][p]
  float*  vals = (float*)w;  w += (size_t)nnz * 4;
  int*    ek   = (int*)w;    w += (size_t)nnz * 4;
  float*  ev   = (float*)w;  w += (size_t)nnz * 4;
  int*    base = (int*)w;    w += NN * 4;
  int*    curs = (int*)w;    w += NN * 4;
  float*  diag = (float*)w;  w += NN * 4;
  int*    empt = (int*)w;    w += NN * 4;
  int*    hist = (int*)w;    w += NN * 4;   // -- zeroed by memset (contiguous) --
  float*  uW   = (float*)w;  w += NN * 4;
  int*    ecnt = (int*)w;    w += 256;

  // zero hist+uW+ecnt BEFORE prep (in-kernel init raced softmax atomics, r8 lesson)
  hipMemsetAsync(hist, 0, NN * 4 + NN * 4 + 256, stream);

  prep_kernel<<<dim3(2560), dim3(256), 0, stream>>>(W1, W2, WT, W2T,
                                                    hist, ecnt,
                                                    eix, e, nnz, vals, diag, empt);
  scan_uw_kernel<<<dim3(9), dim3(256), 0, stream>>>(hist, base, curs, W2, empt,
                                                    ecnt, uW);
  scatter_kernel<<<dim3((nnz + 255) / 256), dim3(256), 0, stream>>>(eix, vals, nnz,
                                                                    curs, ek, ev);
  spmm_kernel<<<dim3(5120), dim3(256), 0, stream>>>(ek, ev, base, hist, W2T,
                                                    diag, empt, uW, WT, x, xb);
  gemm8_kernel<<<dim3(256), dim3(512), 0, stream>>>(xb, WT, out);
}

// Round 11
// 106.546 us; speedup vs baseline: 1.0659x; 1.0659x over previous
//
#include <hip/hip_runtime.h>
#include <hip/hip_bf16.h>
#include <stdint.h>

#define NN 2048
#define LOG2NN 11
#define GK 2048
#define GNC 2048

typedef __bf16 bf16x8 __attribute__((ext_vector_type(8)));
typedef float f32x4 __attribute__((ext_vector_type(4)));

// round-to-nearest-even f32 -> bf16 bits
__device__ __forceinline__ ushort f2bf(float f) {
  uint32_t x = __float_as_uint(f);
  uint32_t r = (x + 0x7fffu + ((x >> 16) & 1u)) >> 16;
  return (ushort)r;
}

__device__ __forceinline__ int lower_bound32(const int* __restrict__ a, int n, int v) {
  int lo = 0, hi = n;
  while (lo < hi) {
    int mid = (lo + hi) >> 1;
    if (a[mid] < v) lo = mid + 1; else hi = mid;
  }
  return lo;
}

// ---------------------------------------------------------------- prep (fused)
// blocks [0,2048): transpose W1/W2 f32 -> bf16^T (64x64 tiles)
// blocks [2048,2560): per-row softmax + column histogram.
// hist/uW/ecnt zeroed by hipMemsetAsync BEFORE this launch (round-8 lesson).
__global__ __launch_bounds__(256) void prep_kernel(
    const float* __restrict__ W1, const float* __restrict__ W2,
    ushort* __restrict__ WT, ushort* __restrict__ W2T,
    int* __restrict__ hist, int* __restrict__ ecnt,
    const int* __restrict__ idx, const float* __restrict__ e, int nnz,
    float* __restrict__ vals, float* __restrict__ diag, int* __restrict__ empty) {
  __shared__ float tile[64][65];
  const int bid = blockIdx.x;
  const int t = threadIdx.x;
  if (bid < 2048) {  // transpose: out[c][r] = (bf16) in[r][c]
    const int m = bid >> 10;            // 0 = W1, 1 = W2
    const int rem = bid & 1023;
    const int r0 = (rem >> 5) * 64, c0 = (rem & 31) * 64;
    const float* in = m ? W2 : W1;
    ushort* out = m ? W2T : WT;
    const int tx = t & 15, ty = t >> 4;
#pragma unroll
    for (int i = 0; i < 4; ++i) {
      int r = i * 16 + ty;
      float4 v = *reinterpret_cast<const float4*>(&in[(size_t)(r0 + r) * NN + c0 + tx * 4]);
      tile[r][tx * 4 + 0] = v.x;
      tile[r][tx * 4 + 1] = v.y;
      tile[r][tx * 4 + 2] = v.z;
      tile[r][tx * 4 + 3] = v.w;
    }
    __syncthreads();
#pragma unroll
    for (int i = 0; i < 4; ++i) {
      int oc = i * 16 + ty;  // output row = original col
      ushort4 o;
      o.x = f2bf(tile[tx * 4 + 0][oc]);
      o.y = f2bf(tile[tx * 4 + 1][oc]);
      o.z = f2bf(tile[tx * 4 + 2][oc]);
      o.w = f2bf(tile[tx * 4 + 3][oc]);
      *reinterpret_cast<ushort4*>(&out[(size_t)(c0 + oc) * NN + r0 + tx * 4]) = o;
    }
  } else {  // softmax + hist: wave w handles row r
    const int w = t >> 6, lane = t & 63;
    const int r = (bid - 2048) * 4 + w;
    int lo = lower_bound32(idx, nnz, r << LOG2NN);
    int hi = lower_bound32(idx, nnz, (r + 1) << LOG2NN);
    if (hi <= lo) {  // empty row: softmax of all-equal NEG -> uniform 1/NN
      if (lane == 0) { diag[r] = 1.0f / NN; empty[r] = 1; atomicAdd(ecnt, 1); }
      return;
    }
    float m = -3.0e38f;
    for (int j = lo + lane; j < hi; j += 64) m = fmaxf(m, e[j]);
#pragma unroll
    for (int s = 32; s >= 1; s >>= 1) m = fmaxf(m, __shfl_xor(m, s));
    float sum = 0.f;
    for (int j = lo + lane; j < hi; j += 64) sum += expf(e[j] - m);
#pragma unroll
    for (int s = 32; s >= 1; s >>= 1) sum += __shfl_xor(sum, s);
    float inv = 1.0f / sum;
    float dv = 0.f;
    for (int j = lo + lane; j < hi; j += 64) {
      float v = expf(e[j] - m) * inv;
      vals[j] = v;
      int c = idx[j] & (NN - 1);
      if (c == r) dv = v;
      else atomicAdd(&hist[c], 1);
    }
#pragma unroll
    for (int s = 32; s >= 1; s >>= 1) dv += __shfl_xor(dv, s);
    if (lane == 0) { diag[r] = dv; empty[r] = 0; }
  }
}

// ---------------------------------------------------------------- scan + uw (fused)
__global__ __launch_bounds__(256) void scan_uw_kernel(
    const int* __restrict__ hist, int* __restrict__ base, int* __restrict__ cursor,
    const float* __restrict__ W2, const int* __restrict__ empty,
    const int* __restrict__ ecnt, float* __restrict__ uW) {
  if (blockIdx.x == 0) {
    const int l = threadIdx.x;
    if (l >= 64) return;
    int vals[32], pre[32];
    int run = 0;
#pragma unroll
    for (int j = 0; j < 32; ++j) {
      vals[j] = hist[l * 32 + j];
      pre[j] = run;
      run += vals[j];
    }
    int tot = run, inc = run;
#pragma unroll
    for (int s = 1; s < 64; s <<= 1) {
      int o = __shfl_up(inc, s);
      if (l >= s) inc += o;
    }
    int excl = inc - tot;
#pragma unroll
    for (int j = 0; j < 32; ++j) {
      int b = excl + pre[j];
      base[l * 32 + j] = b;
      cursor[l * 32 + j] = b;
    }
  } else {
    if (*ecnt == 0) return;
    int p = (blockIdx.x - 1) * 256 + threadIdx.x;
    float s = 0.f;
    for (int k = 0; k < NN; ++k)
      if (empty[k]) s += W2[(size_t)p * NN + k];
    uW[p] = s * (1.0f / NN);
  }
}

// ---------------------------------------------------------------- scatter by column
__global__ void scatter_kernel(const int* __restrict__ idx, const float* __restrict__ vals,
                               int nnz, int* __restrict__ cursor,
                               int* __restrict__ ek, float* __restrict__ ev) {
  int j = blockIdx.x * blockDim.x + threadIdx.x;
  if (j >= nnz) return;
  int f = idx[j];
  int c = f & (NN - 1), r = f >> LOG2NN;
  if (c != r) {
    int p = atomicAdd(&cursor[c], 1);
    ek[p] = r;
    ev[p] = vals[j];
  }
}

// ---------------------------------------------------------------- SpMM + x-convert
__global__ __launch_bounds__(256) void spmm_kernel(
    const int* __restrict__ ek, const float* __restrict__ ev,
    const int* __restrict__ base, const int* __restrict__ hist,
    const ushort* __restrict__ W2T,
    const float* __restrict__ diag, const int* __restrict__ empty,
    const float* __restrict__ uW, ushort* WT,
    const float* __restrict__ x, ushort* __restrict__ xb) {
  if (blockIdx.x >= 1024) {  // x convert: 4096 blocks x 256 thr x 8 floats
    int i = ((int)blockIdx.x - 1024) * 256 + threadIdx.x;
    const float4* in4 = reinterpret_cast<const float4*>(x);
    float4 a = in4[2 * i];
    float4 b = in4[2 * i + 1];
    uint4 o;
    o.x = (uint32_t)f2bf(a.x) | ((uint32_t)f2bf(a.y) << 16);
    o.y = (uint32_t)f2bf(a.z) | ((uint32_t)f2bf(a.w) << 16);
    o.z = (uint32_t)f2bf(b.x) | ((uint32_t)f2bf(b.y) << 16);
    o.w = (uint32_t)f2bf(b.z) | ((uint32_t)f2bf(b.w) << 16);
    reinterpret_cast<uint4*>(xb)[i] = o;
    return;
  }
  const int w = threadIdx.x >> 6, lane = threadIdx.x & 63;
  const int n = blockIdx.x * 2 + (w >> 1);
  const int c0 = (w & 1) * 1024 + lane * 16;  // groups at c0, c0+8
  const int start = base[n], cnt = hist[n];
  float acc[2][8];
#pragma unroll
  for (int g = 0; g < 2; ++g) {
    float4 u0 = *reinterpret_cast<const float4*>(&uW[c0 + g * 8]);
    float4 u1 = *reinterpret_cast<const float4*>(&uW[c0 + g * 8 + 4]);
    acc[g][0] = u0.x; acc[g][1] = u0.y; acc[g][2] = u0.z; acc[g][3] = u0.w;
    acc[g][4] = u1.x; acc[g][5] = u1.y; acc[g][6] = u1.z; acc[g][7] = u1.w;
  }
  float d = diag[n];  // diag term first (reads WT range before overwriting)
  if (d != 0.f) {
#pragma unroll
    for (int g = 0; g < 2; ++g) {
      bf16x8 wd = *reinterpret_cast<const bf16x8*>(&WT[(size_t)n * NN + c0 + g * 8]);
#pragma unroll
      for (int j = 0; j < 8; ++j) acc[g][j] += d * (float)wd[j];
    }
  }
  int i = 0;
  for (; i + 4 <= cnt; i += 4) {
    int k[4];
    float v[4];
    bf16x8 wv[4][2];
#pragma unroll
    for (int e2 = 0; e2 < 4; ++e2) {
      k[e2] = ek[start + i + e2];
      v[e2] = ev[start + i + e2];
    }
#pragma unroll
    for (int e2 = 0; e2 < 4; ++e2)
#pragma unroll
      for (int g = 0; g < 2; ++g)
        wv[e2][g] = *reinterpret_cast<const bf16x8*>(&W2T[(size_t)k[e2] * NN + c0 + g * 8]);
#pragma unroll
    for (int e2 = 0; e2 < 4; ++e2)
#pragma unroll
      for (int g = 0; g < 2; ++g)
#pragma unroll
        for (int j = 0; j < 8; ++j)
          acc[g][j] += v[e2] * (float)wv[e2][g][j];
  }
  for (; i < cnt; ++i) {
    int k0 = ek[start + i];
    float v0 = ev[start + i];
#pragma unroll
    for (int g = 0; g < 2; ++g) {
      bf16x8 w0 = *reinterpret_cast<const bf16x8*>(&W2T[(size_t)k0 * NN + c0 + g * 8]);
#pragma unroll
      for (int j = 0; j < 8; ++j) acc[g][j] += v0 * (float)w0[j];
    }
  }
  if (empty[n]) {
#pragma unroll
    for (int g = 0; g < 2; ++g) {
      bf16x8 we = *reinterpret_cast<const bf16x8*>(&W2T[(size_t)n * NN + c0 + g * 8]);
#pragma unroll
      for (int j = 0; j < 8; ++j) acc[g][j] -= (1.0f / NN) * (float)we[j];
    }
  }
#pragma unroll
  for (int g = 0; g < 2; ++g) {
    uint4 o;
    o.x = (uint32_t)f2bf(acc[g][0]) | ((uint32_t)f2bf(acc[g][1]) << 16);
    o.y = (uint32_t)f2bf(acc[g][2]) | ((uint32_t)f2bf(acc[g][3]) << 16);
    o.z = (uint32_t)f2bf(acc[g][4]) | ((uint32_t)f2bf(acc[g][5]) << 16);
    o.w = (uint32_t)f2bf(acc[g][6]) | ((uint32_t)f2bf(acc[g][7]) << 16);
    *reinterpret_cast<uint4*>(&WT[(size_t)n * NN + c0 + g * 8]) = o;
  }
}

// ---------------------------------------------------------------- 256x128 3-buffer GEMM
// BM=256, BN=128, BK=64, 512 thr (8 waves 4M x 2N, 64x64/wave). LDS = 3 bufs
// (A 3x32KB @0, B 3x16KB @96KB = 144KB): tile kt reads buf kt%3, t+1 waits in
// (kt+1)%3, and (kt+2)%3 is IDLE all tile -> the 6 stage-gloads for t+2 issue
// at the top of the body, fully overlapped with ds_reads+MFMA (no intra-tile
// write/read hazard). ONE barrier + ONE vmcnt(6) per K-tile, no lgkm drains
// (compiler emits counted lgkmcnt). Ledger: 12 gloads outstanding at each
// barrier (t+1:6 old, t+2:6 young) -> vmcnt(6) seals t+1. Wrap stages at
// kt=30,31 keep the ledger uniform (target buffer is free; data never read).
// Read layout/swizzle byte-identical to round-9 (measured 0 conflicts).
__device__ __forceinline__ void gload_lds16(const ushort* g, char* l) {
  __builtin_amdgcn_global_load_lds(
      (__attribute__((address_space(1))) uint32_t*)(uintptr_t)g,
      (__attribute__((address_space(3))) uint32_t*)l, 16, 0, 0);
}

#define NT 32  // K-tiles (2048/64)

__global__ __launch_bounds__(512, 2)
void gemm8_kernel(const ushort* __restrict__ A, const ushort* __restrict__ Bt,
                  float* __restrict__ Cf) {
  __shared__ __align__(16) char smem[147456];  // A: 3x32KB @0 | B: 3x16KB @96KB
  const int t = threadIdx.x;
  const int wid = t >> 6, lane = t & 63;
  const int wm = wid >> 1, wn = wid & 1;     // 4M x 2N wave grid
  const int fr = lane & 15, fg = lane >> 4;

  // XCD-aware swizzle (256 blocks, 256%8==0 -> bijective)
  const int swz = ((int)blockIdx.x & 7) * 32 + ((int)blockIdx.x >> 3);
  const int m0 = (swz >> 4) * 256;
  const int n0 = (swz & 15) * 128;

  // staging: LDS linear dest (base + lane*16 by HW), inverse-swizzled source
  const int l8 = lane >> 3;
  const int scol = ((lane & 7) ^ l8) << 3;  // source col (elements)
  const int srow = wid * 8 + l8;            // row within a 64-row slab

#define STGA(H, TAU, BUF) do {                                                 \
    gload_lds16(A + (size_t)(m0 + (H) * 128 + srow) * GK + (TAU) * 64 + scol,  \
                smem + (BUF) * 32768 + (H) * 16384 + wid * 1024);              \
    gload_lds16(A + (size_t)(m0 + (H) * 128 + 64 + srow) * GK + (TAU) * 64 + scol, \
                smem + (BUF) * 32768 + (H) * 16384 + 8192 + wid * 1024);       \
  } while (0)

#define STGB(TAU, BUF) do {                                                    \
    gload_lds16(Bt + (size_t)(n0 + srow) * GK + (TAU) * 64 + scol,             \
                smem + 98304 + (BUF) * 16384 + wid * 1024);                    \
    gload_lds16(Bt + (size_t)(n0 + 64 + srow) * GK + (TAU) * 64 + scol,        \
                smem + 98304 + (BUF) * 16384 + 8192 + wid * 1024);             \
  } while (0)

  // ds_read addressing (swizzled; round-9 verified, 0 conflicts)
  const int sw = (fr & 7) << 4;
  const int ko0 = (fg * 16) ^ sw;        // ks=0
  const int ko1 = (64 + fg * 16) ^ sw;   // ks=1

  f32x4 acc[4][4] = {};

  // prologue: tile0 -> buf0, tile1 -> buf1
  STGA(0, 0, 0); STGA(1, 0, 0); STGB(0, 0);
  STGA(0, 1, 1); STGA(1, 1, 1); STGB(1, 1);
  asm volatile("s_waitcnt vmcnt(6)" ::: "memory");   // tile0 sealed
  __builtin_amdgcn_s_barrier();
  asm volatile("" ::: "memory");

  for (int kt = 0; kt < NT; ++kt) {
    const int br = kt % 3;              // read buffer
    const int bs = (kt + 2) % 3;        // stage buffer (idle this tile)
    const int t2 = (kt + 2) & (NT - 1); // wrap stages keep ledger uniform
    // stage t+2 first: overlaps with reads + MFMA below (different buffer)
    STGA(0, t2, bs); STGA(1, t2, bs); STGB(t2, bs);

    const char* Ab = smem + br * 32768;
    const char* Bb = smem + 98304 + br * 16384;
    bf16x8 aF[4][2], bF[4][2];
#pragma unroll
    for (int mf = 0; mf < 4; ++mf) {
      const int row = wm * 64 + mf * 16 + fr;
      const char* p = Ab + (row >> 7) * 16384 + (row & 127) * 128;
      aF[mf][0] = *reinterpret_cast<const bf16x8*>(p + ko0);
      aF[mf][1] = *reinterpret_cast<const bf16x8*>(p + ko1);
    }
#pragma unroll
    for (int nf = 0; nf < 4; ++nf) {
      const char* p = Bb + (wn * 64 + nf * 16 + fr) * 128;
      bF[nf][0] = *reinterpret_cast<const bf16x8*>(p + ko0);
      bF[nf][1] = *reinterpret_cast<const bf16x8*>(p + ko1);
    }
    __builtin_amdgcn_s_setprio(1);
#pragma unroll
    for (int mf = 0; mf < 4; ++mf)
#pragma unroll
      for (int nf = 0; nf < 4; ++nf)
        acc[mf][nf] = __builtin_amdgcn_mfma_f32_16x16x32_bf16(
            aF[mf][0], bF[nf][0], acc[mf][nf], 0, 0, 0);
#pragma unroll
    for (int mf = 0; mf < 4; ++mf)
#pragma unroll
      for (int nf = 0; nf < 4; ++nf)
        acc[mf][nf] = __builtin_amdgcn_mfma_f32_16x16x32_bf16(
            aF[mf][1], bF[nf][1], acc[mf][nf], 0, 0, 0);
    __builtin_amdgcn_s_setprio(0);
    // seal t+1 (oldest 6 of the 12 outstanding gloads); publish to all waves
    asm volatile("s_waitcnt vmcnt(6)" ::: "memory");
    __builtin_amdgcn_s_barrier();
    asm volatile("" ::: "memory");
  }

  asm volatile("s_waitcnt vmcnt(0)" ::: "memory");  // drain wrap stages
  const int cr = lane >> 4, cc = lane & 15;
#pragma unroll
  for (int mf = 0; mf < 4; ++mf)
#pragma unroll
    for (int nf = 0; nf < 4; ++nf)
#pragma unroll
      for (int q = 0; q < 4; ++q) {
        int gm = m0 + wm * 64 + mf * 16 + cr * 4 + q;
        int gn = n0 + wn * 64 + nf * 16 + cc;
        Cf[(size_t)gm * GNC + gn] = acc[mf][nf][q];
      }
}

// ---------------------------------------------------------------- launch
extern "C" void kernel_launch(void* const* d_in, const int* in_sizes, int n_in,
                              void* d_out, int out_size, void* d_ws, size_t ws_size,
                              hipStream_t stream) {
  const float* x   = (const float*)d_in[0];  // [8,512,2048] -> [4096][2048]
  const float* W1  = (const float*)d_in[1];  // [2048][2048]
  const float* W2  = (const float*)d_in[2];  // [2048][2048]
  const float* e   = (const float*)d_in[3];  // [nnz]
  const int*   eix = (const int*)d_in[4];    // [nnz] sorted flat indices
  const int nnz = in_sizes[3];
  float* out = (float*)d_out;                // [4096][2048] fp32

  // ws layout: 34.39 MB total (proven-safe size). hist|uW|ecnt contiguous.
  char* w = (char*)d_ws;
  ushort* W2T  = (ushort*)w; w += (size_t)NN * NN * 2;    // 8.4 MB  W2^T bf16 [k][p]
  ushort* WT   = (ushort*)w; w += (size_t)NN * NN * 2;    // 8.4 MB  W1^T then Wfused^T [n][p]
  ushort* xb   = (ushort*)w; w += (size_t)4096 * NN * 2;  // 16.8 MB x bf16 [m][p]
  float*  vals = (float*)w;  w += (size_t)nnz * 4;
  int*    ek   = (int*)w;    w += (size_t)nnz * 4;
  float*  ev   = (float*)w;  w += (size_t)nnz * 4;
  int*    base = (int*)w;    w += NN * 4;
  int*    curs = (int*)w;    w += NN * 4;
  float*  diag = (float*)w;  w += NN * 4;
  int*    empt = (int*)w;    w += NN * 4;
  int*    hist = (int*)w;    w += NN * 4;   // -- zeroed by memset (contiguous) --
  float*  uW   = (float*)w;  w += NN * 4;
  int*    ecnt = (int*)w;    w += 256;

  // zero hist+uW+ecnt BEFORE prep (in-kernel init raced softmax atomics, r8 lesson)
  hipMemsetAsync(hist, 0, NN * 4 + NN * 4 + 256, stream);

  prep_kernel<<<dim3(2560), dim3(256), 0, stream>>>(W1, W2, WT, W2T,
                                                    hist, ecnt,
                                                    eix, e, nnz, vals, diag, empt);
  scan_uw_kernel<<<dim3(9), dim3(256), 0, stream>>>(hist, base, curs, W2, empt,
                                                    ecnt, uW);
  scatter_kernel<<<dim3((nnz + 255) / 256), dim3(256), 0, stream>>>(eix, vals, nnz,
                                                                    curs, ek, ev);
  spmm_kernel<<<dim3(5120), dim3(256), 0, stream>>>(ek, ev, base, hist, W2T,
                                                    diag, empt, uW, WT, x, xb);
  gemm8_kernel<<<dim3(256), dim3(512), 0, stream>>>(xb, WT, out);
}